// Round 1
// baseline (170.945 us; speedup 1.0000x reference)
//
#include <hip/hip_runtime.h>

typedef unsigned int u32;
typedef unsigned long long u64;
typedef unsigned char u8;

// Marching-tets tables (from reference)
__constant__ int c_tt[16][6] = {
  {-1,-1,-1,-1,-1,-1},{1,0,2,-1,-1,-1},{4,0,3,-1,-1,-1},{1,4,2,1,3,4},
  {3,1,5,-1,-1,-1},{2,3,0,2,5,3},{1,4,0,1,5,4},{4,2,5,-1,-1,-1},
  {4,5,2,-1,-1,-1},{4,1,0,4,5,1},{3,2,0,3,5,2},{1,3,5,-1,-1,-1},
  {4,1,2,4,3,1},{3,0,4,-1,-1,-1},{2,0,1,-1,-1,-1},{-1,-1,-1,-1,-1,-1}};
__constant__ int c_ntri[16] = {0,1,1,2,1,2,2,1,1,2,2,1,2,1,1,0};
__constant__ int c_e0[6] = {0,0,0,1,1,2};
__constant__ int c_e1[6] = {1,2,3,2,3,3};

// ---------------- scan helpers (wave64) ----------------
__device__ __forceinline__ u32 wave_incscan_u32(u32 v) {
  int lane = threadIdx.x & 63;
#pragma unroll
  for (int d = 1; d < 64; d <<= 1) {
    u32 n = __shfl_up(v, (unsigned)d, 64);
    if (lane >= d) v += n;
  }
  return v;
}
__device__ __forceinline__ u64 wave_incscan_u64(u64 v) {
  int lane = threadIdx.x & 63;
#pragma unroll
  for (int d = 1; d < 64; d <<= 1) {
    u32 lo = __shfl_up((u32)v, (unsigned)d, 64);
    u32 hi = __shfl_up((u32)(v >> 32), (unsigned)d, 64);
    u64 n = ((u64)hi << 32) | (u64)lo;
    if (lane >= d) v += n;
  }
  return v;
}
// exclusive block scan; wsums must hold blockDim.x/64 entries
__device__ __forceinline__ u32 block_exscan_u32(u32 v, u32* wsums, u32* total) {
  int tid = threadIdx.x, lane = tid & 63, w = tid >> 6, nw = blockDim.x >> 6;
  u32 inc = wave_incscan_u32(v);
  if (lane == 63) wsums[w] = inc;
  __syncthreads();
  u32 woff = 0, tot = 0;
  for (int i = 0; i < nw; i++) { u32 s = wsums[i]; tot += s; if (i < w) woff += s; }
  __syncthreads();
  if (total) *total = tot;
  return woff + inc - v;
}
__device__ __forceinline__ u64 block_exscan_u64(u64 v, u64* wsums, u64* total) {
  int tid = threadIdx.x, lane = tid & 63, w = tid >> 6, nw = blockDim.x >> 6;
  u64 inc = wave_incscan_u64(v);
  if (lane == 63) wsums[w] = inc;
  __syncthreads();
  u64 woff = 0, tot = 0;
  for (int i = 0; i < nw; i++) { u64 s = wsums[i]; tot += s; if (i < w) woff += s; }
  __syncthreads();
  if (total) *total = tot;
  return woff + inc - v;
}

// ---------------- kernels ----------------
__global__ void k_pos_occ(const float* __restrict__ verts, const float* __restrict__ sdf,
                          const float* __restrict__ deform, float* __restrict__ pos,
                          u8* __restrict__ occ, int NV, float s) {
  int v = blockIdx.x * blockDim.x + threadIdx.x;
  if (v >= NV) return;
  occ[v] = sdf[v] > 0.0f ? 1 : 0;
  pos[3 * v + 0] = verts[3 * v + 0] + s * tanhf(deform[3 * v + 0]);
  pos[3 * v + 1] = verts[3 * v + 1] + s * tanhf(deform[3 * v + 1]);
  pos[3 * v + 2] = verts[3 * v + 2] + s * tanhf(deform[3 * v + 2]);
}

// per-vertex crossing mask over 7 outgoing edges (sorted-Delta order) + block sums
__global__ void k_mask(const u8* __restrict__ occ, u8* __restrict__ vmask,
                       u32* __restrict__ bsum, int NV, int R, int R1, int R1sq) {
  __shared__ u32 ws[4];
  int v = blockIdx.x * blockDim.x + threadIdx.x;
  u32 cnt = 0;
  if (v < NV) {
    int z = v % R1, t = v / R1, y = t % R1, x = t / R1;
    u8 o = occ[v];
    u8 m = 0;
    bool bx = x < R, by = y < R, bz = z < R;
    if (bz && occ[v + 1] != o) m |= 1;                       // (0,0,1)
    if (by && occ[v + R1] != o) m |= 2;                      // (0,1,0)
    if (by && bz && occ[v + R1 + 1] != o) m |= 4;            // (0,1,1)
    if (bx && occ[v + R1sq] != o) m |= 8;                    // (1,0,0)
    if (bx && bz && occ[v + R1sq + 1] != o) m |= 16;         // (1,0,1)
    if (bx && by && occ[v + R1sq + R1] != o) m |= 32;        // (1,1,0)
    if (bx && by && bz && occ[v + R1sq + R1 + 1] != o) m |= 64; // (1,1,1)
    vmask[v] = m;
    cnt = __popc((u32)m);
  }
  u32 tot;
  block_exscan_u32(cnt, ws, &tot);
  if (threadIdx.x == 0) bsum[blockIdx.x] = tot;
}

// single-block exclusive scan of block sums (u32); writes total E to hdr_slot[0]
__global__ void k_scan_aux_u32(const u32* __restrict__ in, u32* __restrict__ out, int n,
                               u32* __restrict__ hdr_slot) {
  __shared__ u32 ws[16];
  u32 carry = 0;
  for (int base = 0; base < n; base += blockDim.x) {
    int i = base + threadIdx.x;
    u32 v = (i < n) ? in[i] : 0;
    u32 tot;
    u32 ex = block_exscan_u32(v, ws, &tot);
    if (i < n) out[i] = carry + ex;
    carry += tot;
  }
  if (threadIdx.x == 0) hdr_slot[0] = carry;
}
// single-block exclusive scan of packed (m1|m2<<32) block sums; totals -> hdr[1],hdr[2]
__global__ void k_scan_aux_u64(const u64* __restrict__ in, u64* __restrict__ out, int n,
                               u32* __restrict__ hdr) {
  __shared__ u64 ws[16];
  u64 carry = 0;
  for (int base = 0; base < n; base += blockDim.x) {
    int i = base + threadIdx.x;
    u64 v = (i < n) ? in[i] : 0;
    u64 tot;
    u64 ex = block_exscan_u64(v, ws, &tot);
    if (i < n) out[i] = carry + ex;
    carry += tot;
  }
  if (threadIdx.x == 0) { hdr[1] = (u32)carry; hdr[2] = (u32)(carry >> 32); }
}

__global__ void k_vbase(const u8* __restrict__ vmask, const u32* __restrict__ boff,
                        u32* __restrict__ vbase, int NV) {
  __shared__ u32 ws[4];
  int v = blockIdx.x * blockDim.x + threadIdx.x;
  u32 cnt = (v < NV) ? __popc((u32)vmask[v]) : 0;
  u32 ex = block_exscan_u32(cnt, ws, nullptr);
  if (v < NV) vbase[v] = boff[blockIdx.x] + ex;
}

// per-tet occupancy code + packed (m1 | m2<<16) block sums (stored widened to u64)
__global__ void k_tcode(const int* __restrict__ tets, const u8* __restrict__ occ,
                        u8* __restrict__ tcode, u64* __restrict__ bsum, int T) {
  __shared__ u32 ws[4];
  int t = blockIdx.x * blockDim.x + threadIdx.x;
  u32 packed = 0;
  if (t < T) {
    int4 q = reinterpret_cast<const int4*>(tets)[t];
    int code = (int)occ[q.x] | ((int)occ[q.y] << 1) | ((int)occ[q.z] << 2) | ((int)occ[q.w] << 3);
    tcode[t] = (u8)code;
    int n = c_ntri[code];
    packed = (n == 1 ? 1u : 0u) | (n == 2 ? (1u << 16) : 0u);
  }
  u32 tot;
  block_exscan_u32(packed, ws, &tot);
  if (threadIdx.x == 0) bsum[blockIdx.x] = (u64)(tot & 0xffffu) | ((u64)(tot >> 16) << 32);
}

__global__ void k_tetscan(const u8* __restrict__ tcode, const u64* __restrict__ boff,
                          u64* __restrict__ tetscan, int T) {
  __shared__ u32 ws[4];
  int t = blockIdx.x * blockDim.x + threadIdx.x;
  u32 packed = 0;
  if (t < T) {
    int n = c_ntri[tcode[t]];
    packed = (n == 1 ? 1u : 0u) | (n == 2 ? (1u << 16) : 0u);
  }
  u32 ex = block_exscan_u32(packed, ws, nullptr);
  if (t < T) {
    u64 bo = boff[blockIdx.x];
    u32 s1 = (u32)bo + (ex & 0xffffu);
    u32 s2 = (u32)(bo >> 32) + (ex >> 16);
    tetscan[t] = (u64)s1 | ((u64)s2 << 32);
  }
}

// uvs section: data-independent values at device-computed offset 3E+3F
__global__ void k_uvs(float* __restrict__ out, const u32* __restrict__ hdr, int NU) {
  long long i = (long long)blockIdx.x * blockDim.x + threadIdx.x;
  long long ncell = (long long)NU * NU;
  if (i >= ncell) return;
  u32 E = hdr[0], F = hdr[1] + 2u * hdr[2];
  size_t base = (size_t)3 * E + (size_t)3 * F + (size_t)8 * i;
  int row = (int)(i / NU), col = (int)(i % NU);
  double inv = 1.0 / (double)NU;
  float x = (float)((double)col * inv);
  float y = (float)((double)row * inv);
  float pad = (float)(0.9 * inv);
  float xp = x + pad, yp = y + pad;
  out[base + 0] = x;  out[base + 1] = y;
  out[base + 2] = xp; out[base + 3] = y;
  out[base + 4] = xp; out[base + 5] = yp;
  out[base + 6] = x;  out[base + 7] = yp;
}

// interpolated crossing vertices, in (v, Delta-ascending) order == jnp.unique order
__global__ void k_verts(const float* __restrict__ pos, const float* __restrict__ sdf,
                        const u8* __restrict__ vmask, const u32* __restrict__ vbase,
                        float* __restrict__ out, int NV, int R1, int R1sq) {
  int v = blockIdx.x * blockDim.x + threadIdx.x;
  if (v >= NV) return;
  u32 m = vmask[v];
  if (!m) return;
  int deltas[7] = {1, R1, R1 + 1, R1sq, R1sq + 1, R1sq + R1, R1sq + R1 + 1};
  float pa0 = pos[3 * v], pa1 = pos[3 * v + 1], pa2 = pos[3 * v + 2];
  float sa = sdf[v];
  u32 r = vbase[v];
#pragma unroll
  for (int k = 0; k < 7; k++) {
    if ((m >> k) & 1) {
      int b = v + deltas[k];
      float sb = sdf[b];
      float den = sa - sb;           // sign differs -> no cancellation
      float w0 = -sb / den, w1 = sa / den;
      out[3 * r + 0] = pa0 * w0 + pos[3 * b + 0] * w1;
      out[3 * r + 1] = pa1 * w0 + pos[3 * b + 1] * w1;
      out[3 * r + 2] = pa2 * w0 + pos[3 * b + 2] * w1;
      r++;
    }
  }
}

// faces (as float) + uv_idx (as float), m1 block then m2 pairs
__global__ void k_faces(const int* __restrict__ tets, const u8* __restrict__ tcode,
                        const u64* __restrict__ tetscan, const u32* __restrict__ vbase,
                        const u8* __restrict__ vmask, const u32* __restrict__ hdr,
                        float* __restrict__ out, int T, int R1, int R1sq, long long uvtot) {
  int t = blockIdx.x * blockDim.x + threadIdx.x;
  if (t >= T) return;
  int code = tcode[t];
  int n = c_ntri[code];
  if (n == 0) return;
  u64 s = tetscan[t];
  u32 s1 = (u32)s, s2 = (u32)(s >> 32);
  u32 E = hdr[0], F1 = hdr[1], F2 = hdr[2];
  u32 F = F1 + 2u * F2;
  size_t fb = (size_t)3 * E;
  size_t ub = fb + (size_t)3 * F + (size_t)uvtot;
  int4 q = reinterpret_cast<const int4*>(tets)[t];
  int vv[4] = {q.x, q.y, q.z, q.w};
  for (int tri = 0; tri < n; tri++) {
    u32 row = (n == 1) ? s1 : (F1 + 2u * s2 + (u32)tri);
#pragma unroll
    for (int j = 0; j < 3; j++) {
      int slot = c_tt[code][3 * tri + j];
      int va = vv[c_e0[slot]], vb = vv[c_e1[slot]];
      if (va > vb) { int tmp = va; va = vb; vb = tmp; }
      int d = vb - va;
      int dx = d >= R1sq ? 1 : 0; d -= dx * R1sq;
      int dy = d >= R1 ? 1 : 0;   d -= dy * R1;      // d now dz in {0,1}
      int k = (dx << 2) + (dy << 1) + d - 1;         // slot in sorted-Delta order
      u32 fidx = vbase[va] + __popc((u32)vmask[va] & ((1u << k) - 1u));
      out[fb + 3 * row + j] = (float)fidx;
    }
    // uv_idx: face_gidx g = 2t+tri (m2) or 2t (m1, tri==0); g>>1 == t, g&1 == tri
    out[ub + 3 * row + 0] = (float)(4 * t);
    out[ub + 3 * row + 1] = (float)(4 * t + tri + 1);
    out[ub + 3 * row + 2] = (float)(4 * t + tri + 2);
  }
}

extern "C" void kernel_launch(void* const* d_in, const int* in_sizes, int n_in,
                              void* d_out, int out_size, void* d_ws, size_t ws_size,
                              hipStream_t stream) {
  const float* verts = (const float*)d_in[0];
  const float* sdf = (const float*)d_in[1];
  const float* deform = (const float*)d_in[2];
  const int* tets = (const int*)d_in[3];   // JAX default x64-off: int32
  int NV = in_sizes[0] / 3;
  int T = in_sizes[3] / 4;
  int R = 1;
  while ((long long)(R + 1) * (R + 1) * (R + 1) < (long long)NV) R++;
  int R1 = R + 1, R1sq = R1 * R1;
  int NU = 1;
  while ((long long)NU * NU < (long long)T) NU++;   // N = ceil(sqrt((2T+1)//2)) = ceil(sqrt(T))
  long long UVTOT = 8LL * NU * NU;
  int Bv = (NV + 255) / 256, Bt = (T + 255) / 256;

  // workspace carve (u64 first for alignment); total ~19.2 MB
  char* w = (char*)d_ws;
  u64* tetscan = (u64*)w; w += (size_t)T * 8;
  u64* bsumT = (u64*)w;   w += (size_t)Bt * 8;
  u64* boffT = (u64*)w;   w += (size_t)Bt * 8;
  float* pos = (float*)w; w += (size_t)NV * 12;
  u32* vbase = (u32*)w;   w += (size_t)NV * 4;
  u32* bsumV = (u32*)w;   w += (size_t)Bv * 4;
  u32* boffV = (u32*)w;   w += (size_t)Bv * 4;
  u32* hdr = (u32*)w;     w += 16;
  u8* occ = (u8*)w;       w += NV;
  u8* vmask = (u8*)w;     w += NV;
  u8* tcode = (u8*)w;     w += T;

  float sdef = 2.0f / (float)(R * 2);   // 1/64 = 0.015625 exact
  float* outf = (float*)d_out;

  k_pos_occ<<<dim3((NV + 255) / 256), dim3(256), 0, stream>>>(verts, sdf, deform, pos, occ, NV, sdef);
  k_mask<<<dim3(Bv), dim3(256), 0, stream>>>(occ, vmask, bsumV, NV, R, R1, R1sq);
  k_scan_aux_u32<<<dim3(1), dim3(1024), 0, stream>>>(bsumV, boffV, Bv, hdr);
  k_vbase<<<dim3(Bv), dim3(256), 0, stream>>>(vmask, boffV, vbase, NV);
  k_tcode<<<dim3(Bt), dim3(256), 0, stream>>>(tets, occ, tcode, bsumT, T);
  k_scan_aux_u64<<<dim3(1), dim3(1024), 0, stream>>>(bsumT, boffT, Bt, hdr);
  k_tetscan<<<dim3(Bt), dim3(256), 0, stream>>>(tcode, boffT, tetscan, T);
  k_uvs<<<dim3((int)(((long long)NU * NU + 255) / 256)), dim3(256), 0, stream>>>(outf, hdr, NU);
  k_verts<<<dim3((NV + 255) / 256), dim3(256), 0, stream>>>(pos, sdf, vmask, vbase, outf, NV, R1, R1sq);
  k_faces<<<dim3(Bt), dim3(256), 0, stream>>>(tets, tcode, tetscan, vbase, vmask, hdr, outf, T, R1, R1sq, UVTOT);
}